// Round 4
// baseline (366.708 us; speedup 1.0000x reference)
//
#include <hip/hip_runtime.h>
#include <hip/hip_cooperative_groups.h>

// EMA recurrence over s for x[4, 4096, 2048] fp32.
// Single cooperative kernel, exact chunked scan:
//   phase 1: per-(col4, chunk j) local EMA (zero init) -> chunk final f_j in ws
//   grid.sync()
//   phase 2: carry E_{j-1} = Horner over f_0..f_{j-1} with alpha^L, rescan the
//            chunk from x (L3-resident after phase 1) with correct carry,
//            nontemporal store to out.

namespace cg = cooperative_groups;

namespace {

constexpr int B  = 4;
constexpr int S  = 4096;
constexpr int D  = 2048;
constexpr int D4 = D / 4;          // 512 float4 per (b,s) row
constexpr int NCOL4 = B * D4;      // 2048 float4-columns
constexpr int BLOCK = 256;

// Native vector type for nontemporal builtins (HIP_vector_type is rejected).
typedef float v4f __attribute__((ext_vector_type(4)));

// Match the reference's fp32 constants exactly:
// alpha = float32(0.99); one_m = float32(1.0 - 0.99)
constexpr float kA  = 0.99f;
constexpr float kOm = (float)(1.0 - 0.99);      // 0.009999999776482582f

// 0.99^L in double, L a power of two (repeated squaring), then round to float.
constexpr double alpha_pow_pow2(int l) {
    double t = 0.99;
    while (l > 1) { t *= t; l >>= 1; }
    return t;
}

template <int NCHUNK>
__global__ __launch_bounds__(BLOCK, 4)   // 16 waves/CU -> 4 blocks/CU co-resident
void cema_fused(const float4* __restrict__ x, float4* __restrict__ ws,
                float4* __restrict__ out) {
    constexpr int L = S / NCHUNK;
    constexpr float aL = (float)alpha_pow_pow2(L);

    const int c  = blockIdx.x * BLOCK + threadIdx.x;   // col4 index, 0..NCOL4-1
    const int j  = blockIdx.y;                         // chunk index
    const int b  = c >> 9;                             // c / D4
    const int d4 = c & (D4 - 1);

    const size_t base = ((size_t)b * S + (size_t)j * L) * D4 + d4;
    const float4* p = x + base;

    // ---- phase 1: local EMA over this chunk, zero init -> chunk final ----
    {
        float e0 = 0.f, e1 = 0.f, e2 = 0.f, e3 = 0.f;
#pragma unroll 8
        for (int t = 0; t < L; ++t) {
            float4 v = p[(size_t)t * D4];
            e0 = kA * e0 + kOm * v.x;
            e1 = kA * e1 + kOm * v.y;
            e2 = kA * e2 + kOm * v.z;
            e3 = kA * e3 + kOm * v.w;
        }
        ws[(size_t)j * NCOL4 + c] = make_float4(e0, e1, e2, e3);
    }

    cg::this_grid().sync();

    // ---- phase 2: carry via Horner over earlier finals, then rescan ----
    float E0 = 0.f, E1 = 0.f, E2 = 0.f, E3 = 0.f;
#pragma unroll 4
    for (int i = 0; i < j; ++i) {     // j is block-uniform: no divergence
        float4 f = ws[(size_t)i * NCOL4 + c];
        E0 = E0 * aL + f.x;
        E1 = E1 * aL + f.y;
        E2 = E2 * aL + f.z;
        E3 = E3 * aL + f.w;
    }

    v4f* q = (v4f*)(out + base);
#pragma unroll 8
    for (int t = 0; t < L; ++t) {
        float4 v = p[(size_t)t * D4];
        E0 = kA * E0 + kOm * v.x;
        E1 = kA * E1 + kOm * v.y;
        E2 = kA * E2 + kOm * v.z;
        E3 = kA * E3 + kOm * v.w;
        v4f o = {E0, E1, E2, E3};
        __builtin_nontemporal_store(o, &q[(size_t)t * D4]);
    }
}

template <int NCHUNK>
void launch(const float4* x, float4* ws, float4* out, hipStream_t stream) {
    dim3 grid(NCOL4 / BLOCK, NCHUNK);
    void* args[] = {(void*)&x, (void*)&ws, (void*)&out};
    hipLaunchCooperativeKernel((const void*)cema_fused<NCHUNK>, grid, dim3(BLOCK),
                               args, 0, stream);
}

} // namespace

extern "C" void kernel_launch(void* const* d_in, const int* in_sizes, int n_in,
                              void* d_out, int out_size, void* d_ws, size_t ws_size,
                              hipStream_t stream) {
    const float4* x  = (const float4*)d_in[0];
    float4* out      = (float4*)d_out;
    float4* ws       = (float4*)d_ws;

    // Pick the largest chunk count whose finals table fits d_ws.
    const size_t per_chunk = (size_t)NCOL4 * sizeof(float4);
    if (ws_size >= 128 * per_chunk)      launch<128>(x, ws, out, stream);
    else if (ws_size >= 64 * per_chunk)  launch<64>(x, ws, out, stream);
    else                                 launch<32>(x, ws, out, stream);
}